// Round 6
// baseline (682.958 us; speedup 1.0000x reference)
//
#include <hip/hip_runtime.h>

#define FEAT 64
#define HID 10
#define RS 16    // padded row stride (floats) -> 64B rows, one cache line
#define EPB 1024 // edges per block in binning passes (256 thr x 4) -> ~1221 blocks
#define BSH 6    // bucket shift: 64 nodes per bucket

// ---------- Layer-0 precompute: A = X @ W2[0:64,:], B = X @ W2[64:128,:] ----------
__global__ __launch_bounds__(256) void pre_l0(
    const float* __restrict__ X,    // [NN,64]
    const float* __restrict__ W2,   // [128,10]
    float* __restrict__ A,          // [NN,RS]
    float* __restrict__ B,          // [NN,RS]
    int n_nodes)
{
    __shared__ float w2[128 * 10];
    for (int i = threadIdx.x; i < 1280; i += 256) w2[i] = W2[i];
    __syncthreads();

    int n = blockIdx.x * 256 + threadIdx.x;
    if (n >= n_nodes) return;

    const float4* xr = reinterpret_cast<const float4*>(X + (size_t)n * FEAT);
    float a[10], b[10];
#pragma unroll
    for (int h = 0; h < 10; h++) { a[h] = 0.f; b[h] = 0.f; }

#pragma unroll
    for (int blk = 0; blk < 16; blk++) {
        float4 u = xr[blk];
        float xv[4] = { u.x, u.y, u.z, u.w };
#pragma unroll
        for (int j = 0; j < 4; j++) {
            int k = blk * 4 + j;
#pragma unroll
            for (int h = 0; h < 10; h++) {
                a[h] = fmaf(xv[j], w2[k * 10 + h], a[h]);
                b[h] = fmaf(xv[j], w2[(64 + k) * 10 + h], b[h]);
            }
        }
    }

    float4* Ar = reinterpret_cast<float4*>(A + (size_t)n * RS);
    float4* Br = reinterpret_cast<float4*>(B + (size_t)n * RS);
    Ar[0] = make_float4(a[0], a[1], a[2], a[3]);
    Ar[1] = make_float4(a[4], a[5], a[6], a[7]);
    Ar[2] = make_float4(a[8], a[9], 0.f, 0.f);
    Br[0] = make_float4(b[0], b[1], b[2], b[3]);
    Br[1] = make_float4(b[4], b[5], b[6], b[7]);
    Br[2] = make_float4(b[8], b[9], 0.f, 0.f);
}

// ---------- Layers 1/2 precompute: A = H @ W2[0:10,:], B = H @ W2[10:20,:] ----------
__global__ __launch_bounds__(256) void pre_small(
    const float* __restrict__ H,    // [NN,RS]
    const float* __restrict__ W2,   // [20,10]
    float* __restrict__ A,          // [NN,RS]
    float* __restrict__ B,          // [NN,RS]
    int n_nodes)
{
    __shared__ float w2[200];
    for (int i = threadIdx.x; i < 200; i += 256) w2[i] = W2[i];
    __syncthreads();

    int n = blockIdx.x * 256 + threadIdx.x;
    if (n >= n_nodes) return;

    const float4* hr = reinterpret_cast<const float4*>(H + (size_t)n * RS);
    float4 h0 = hr[0], h1 = hr[1], h2 = hr[2];
    float hv[10] = { h0.x, h0.y, h0.z, h0.w, h1.x, h1.y, h1.z, h1.w, h2.x, h2.y };

    float a[10], b[10];
#pragma unroll
    for (int h = 0; h < 10; h++) { a[h] = 0.f; b[h] = 0.f; }
#pragma unroll
    for (int k = 0; k < 10; k++) {
#pragma unroll
        for (int h = 0; h < 10; h++) {
            a[h] = fmaf(hv[k], w2[k * 10 + h], a[h]);
            b[h] = fmaf(hv[k], w2[(10 + k) * 10 + h], b[h]);
        }
    }

    float4* Ar = reinterpret_cast<float4*>(A + (size_t)n * RS);
    float4* Br = reinterpret_cast<float4*>(B + (size_t)n * RS);
    Ar[0] = make_float4(a[0], a[1], a[2], a[3]);
    Ar[1] = make_float4(a[4], a[5], a[6], a[7]);
    Ar[2] = make_float4(a[8], a[9], 0.f, 0.f);
    Br[0] = make_float4(b[0], b[1], b[2], b[3]);
    Br[1] = make_float4(b[4], b[5], b[6], b[7]);
    Br[2] = make_float4(b[8], b[9], 0.f, 0.f);
}

// ================= CSR build: two-level counting sort, LDS cursors only =================

// Pass 1: per-block histogram over coarse buckets (dst >> BSH). No global atomics.
__global__ __launch_bounds__(256) void bin_hist_k(
    const int* __restrict__ dst, int* __restrict__ blockhist, int n_edges, int nbk)
{
    extern __shared__ int hist[];  // nbk ints
    for (int i = threadIdx.x; i < nbk; i += 256) hist[i] = 0;
    __syncthreads();
    int base = blockIdx.x * EPB;
    for (int i = threadIdx.x; i < EPB; i += 256) {
        int e = base + i;
        if (e < n_edges) atomicAdd(&hist[dst[e] >> BSH], 1);  // LDS atomic
    }
    __syncthreads();
    int* row = blockhist + (size_t)blockIdx.x * nbk;
    for (int i = threadIdx.x; i < nbk; i += 256) row[i] = hist[i];
}

// Pass 2a: bucket totals = column sums of blockhist.
__global__ __launch_bounds__(256) void col_sum_k(
    const int* __restrict__ blockhist, int* __restrict__ btot, int nbk, int nblk)
{
    int b = blockIdx.x * 256 + threadIdx.x;
    if (b >= nbk) return;
    int s = 0;
    for (int k = 0; k < nblk; k++) s += blockhist[(size_t)k * nbk + b];
    btot[b] = s;
}

// Pass 2b: single-block exclusive scan of btot (nbk <= 2048).
__global__ __launch_bounds__(256) void scan_k(
    const int* __restrict__ btot, int* __restrict__ bbase,
    int* __restrict__ bucket_start, int* __restrict__ start,
    int nbk, int n_nodes, int n_edges)
{
    __shared__ int ts[256];
    int t = threadIdx.x;
    int v[8];
    int s = 0;
#pragma unroll
    for (int j = 0; j < 8; j++) {
        int idx = t * 8 + j;
        v[j] = (idx < nbk) ? btot[idx] : 0;
        s += v[j];
    }
    ts[t] = s;
    __syncthreads();
    for (int off = 1; off < 256; off <<= 1) {
        int x = (t >= off) ? ts[t - off] : 0;
        __syncthreads();
        ts[t] += x;
        __syncthreads();
    }
    int run = ts[t] - s;
#pragma unroll
    for (int j = 0; j < 8; j++) {
        int idx = t * 8 + j;
        if (idx < nbk) { bbase[idx] = run; bucket_start[idx] = run; }
        run += v[j];
    }
    if (t == 255) { bucket_start[nbk] = n_edges; start[n_nodes] = n_edges; }
}

// Pass 2c: per-bucket running offsets over blocks (in place).
__global__ __launch_bounds__(256) void col_off_k(
    int* __restrict__ blockhist, const int* __restrict__ bbase, int nbk, int nblk)
{
    int b = blockIdx.x * 256 + threadIdx.x;
    if (b >= nbk) return;
    int run = bbase[b];
    for (int k = 0; k < nblk; k++) {
        size_t idx = (size_t)k * nbk + b;
        int c = blockhist[idx];
        blockhist[idx] = run;
        run += c;
    }
}

// Pass 3: bucket-grouped scatter of packed (dloc<<17 | src); cursors in LDS.
__global__ __launch_bounds__(256) void bin_scatter_k(
    const int* __restrict__ src, const int* __restrict__ dst,
    const int* __restrict__ blockhist, int* __restrict__ packed,
    int n_edges, int nbk)
{
    extern __shared__ int cur[];  // nbk ints
    const int* row = blockhist + (size_t)blockIdx.x * nbk;
    for (int i = threadIdx.x; i < nbk; i += 256) cur[i] = row[i];
    __syncthreads();
    int base = blockIdx.x * EPB;
    for (int i = threadIdx.x; i < EPB; i += 256) {
        int e = base + i;
        if (e < n_edges) {
            int d = dst[e];
            int pos = atomicAdd(&cur[d >> BSH], 1);  // LDS atomic
            packed[pos] = ((d & 63) << 17) | src[e];
        }
    }
}

// Pass 4: one block per bucket -> exact CSR (start + nbr), all cursors in LDS.
__global__ __launch_bounds__(256) void csr_k(
    const int* __restrict__ packed, const int* __restrict__ bucket_start,
    int* __restrict__ nbr, int* __restrict__ start, int n_nodes)
{
    __shared__ int hist[64];
    __shared__ int excl[64];
    __shared__ int cur[64];
    int b = blockIdx.x;
    int base = bucket_start[b];
    int end  = bucket_start[b + 1];
    if (threadIdx.x < 64) hist[threadIdx.x] = 0;
    __syncthreads();
    for (int i = base + threadIdx.x; i < end; i += 256)
        atomicAdd(&hist[packed[i] >> 17], 1);  // LDS atomic
    __syncthreads();
    if (threadIdx.x == 0) {
        int r = 0;
        for (int k = 0; k < 64; k++) { excl[k] = r; r += hist[k]; }
    }
    __syncthreads();
    if (threadIdx.x < 64) {
        cur[threadIdx.x] = excl[threadIdx.x];
        int node = (b << 6) + threadIdx.x;
        if (node < n_nodes) start[node] = base + excl[threadIdx.x];
    }
    __syncthreads();
    for (int i = base + threadIdx.x; i < end; i += 256) {
        int p = packed[i];
        int pos = base + atomicAdd(&cur[p >> 17], 1);  // LDS atomic
        nbr[pos] = p & 0x1FFFF;
    }
}

// ---------- Gather-aggregate (quad-per-node): H[n] = 0.1 * sum relu(relu(A[n]+B[s])@W1) ----------
__global__ __launch_bounds__(256) void gather_k(
    const float* __restrict__ A,
    const float* __restrict__ B,
    const float* __restrict__ W1,   // [10,10]
    const int* __restrict__ start,  // [NN+1]
    const int* __restrict__ nbr,    // [NE] src ids grouped by dst
    float* __restrict__ H,          // [NN,RS]
    int n_nodes)
{
    __shared__ float w1[100];
    for (int i = threadIdx.x; i < 100; i += 256) w1[i] = W1[i];
    __syncthreads();

    int t = blockIdx.x * 256 + threadIdx.x;
    int n = t >> 2;
    int q = t & 3;
    if (n >= n_nodes) return;

    const float4* ar = reinterpret_cast<const float4*>(A + (size_t)n * RS);
    float4 a0 = ar[0], a1 = ar[1], a2 = ar[2];
    float av[10] = { a0.x, a0.y, a0.z, a0.w, a1.x, a1.y, a1.z, a1.w, a2.x, a2.y };

    float acc[10];
#pragma unroll
    for (int h = 0; h < 10; h++) acc[h] = 0.f;

    int beg = start[n];
    int end = start[n + 1];
    for (int i = beg + q; i < end; i += 4) {
        int s = nbr[i];
        const float4* br = reinterpret_cast<const float4*>(B + (size_t)s * RS);
        float4 b0 = br[0], b1 = br[1], b2 = br[2];
        float pre[10] = { av[0] + b0.x, av[1] + b0.y, av[2] + b0.z, av[3] + b0.w,
                          av[4] + b1.x, av[5] + b1.y, av[6] + b1.z, av[7] + b1.w,
                          av[8] + b2.x, av[9] + b2.y };
#pragma unroll
        for (int j = 0; j < 10; j++) pre[j] = fmaxf(pre[j], 0.f);
#pragma unroll
        for (int h = 0; h < 10; h++) {
            float z = 0.f;
#pragma unroll
            for (int j = 0; j < 10; j++) z = fmaf(pre[j], w1[j * 10 + h], z);
            acc[h] += fmaxf(z, 0.f);
        }
    }

#pragma unroll
    for (int h = 0; h < 10; h++) acc[h] += __shfl_xor(acc[h], 1);
#pragma unroll
    for (int h = 0; h < 10; h++) acc[h] += __shfl_xor(acc[h], 2);

    if (q == 0) {
        float4* Hr = reinterpret_cast<float4*>(H + (size_t)n * RS);
        Hr[0] = make_float4(acc[0] * 0.1f, acc[1] * 0.1f, acc[2] * 0.1f, acc[3] * 0.1f);
        Hr[1] = make_float4(acc[4] * 0.1f, acc[5] * 0.1f, acc[6] * 0.1f, acc[7] * 0.1f);
        Hr[2] = make_float4(acc[8] * 0.1f, acc[9] * 0.1f, 0.f, 0.f);
    }
}

// ---------- Final node MLP (tiled): out = relu(relu(H@Wf1)@Wf2) ----------
__global__ __launch_bounds__(256) void final_k(
    const float* __restrict__ H,    // [NN,RS]
    const float* __restrict__ Wf1,  // [10,64]
    const float* __restrict__ Wf2,  // [64,64]
    float* __restrict__ out,        // [NN,64]
    int n_nodes)
{
    __shared__ float wf1[640];
    __shared__ float wf2s[64 * 64];
    __shared__ float tT[64 * 64];

    for (int i = threadIdx.x; i < 640; i += 256) wf1[i] = Wf1[i];
    {
        const float4* w2v = reinterpret_cast<const float4*>(Wf2);
        float4* w2s = reinterpret_cast<float4*>(wf2s);
        for (int i = threadIdx.x; i < 1024; i += 256) w2s[i] = w2v[i];
    }

    int node0 = blockIdx.x * 64;

    {
        int r = threadIdx.x & 63;
        int g = threadIdx.x >> 6;
        int node = node0 + r;
        float hv[10];
        if (node < n_nodes) {
            const float4* hr = reinterpret_cast<const float4*>(H + (size_t)node * RS);
            float4 h0 = hr[0], h1 = hr[1], h2 = hr[2];
            hv[0]=h0.x; hv[1]=h0.y; hv[2]=h0.z; hv[3]=h0.w;
            hv[4]=h1.x; hv[5]=h1.y; hv[6]=h1.z; hv[7]=h1.w;
            hv[8]=h2.x; hv[9]=h2.y;
        } else {
#pragma unroll
            for (int k = 0; k < 10; k++) hv[k] = 0.f;
        }
        __syncthreads();
#pragma unroll
        for (int j = 0; j < 16; j++) {
            int c = g * 16 + j;
            float v = 0.f;
#pragma unroll
            for (int k = 0; k < 10; k++) v = fmaf(hv[k], wf1[k * 64 + c], v);
            tT[c * 64 + r] = fmaxf(v, 0.f);
        }
    }
    __syncthreads();

    int r0 = (threadIdx.x >> 4) * 4;
    int c0 = (threadIdx.x & 15) * 4;
    float acc[4][4];
#pragma unroll
    for (int i = 0; i < 4; i++)
#pragma unroll
        for (int j = 0; j < 4; j++) acc[i][j] = 0.f;

    for (int k = 0; k < 64; k++) {
        float4 a = *reinterpret_cast<const float4*>(&tT[k * 64 + r0]);
        float4 b = *reinterpret_cast<const float4*>(&wf2s[k * 64 + c0]);
        float av[4] = { a.x, a.y, a.z, a.w };
        float bv[4] = { b.x, b.y, b.z, b.w };
#pragma unroll
        for (int i = 0; i < 4; i++)
#pragma unroll
            for (int j = 0; j < 4; j++)
                acc[i][j] = fmaf(av[i], bv[j], acc[i][j]);
    }

#pragma unroll
    for (int i = 0; i < 4; i++) {
        int node = node0 + r0 + i;
        if (node < n_nodes) {
            float4 o = make_float4(fmaxf(acc[i][0], 0.f), fmaxf(acc[i][1], 0.f),
                                   fmaxf(acc[i][2], 0.f), fmaxf(acc[i][3], 0.f));
            *reinterpret_cast<float4*>(&out[(size_t)node * FEAT + c0]) = o;
        }
    }
}

extern "C" void kernel_launch(void* const* d_in, const int* in_sizes, int n_in,
                              void* d_out, int out_size, void* d_ws, size_t ws_size,
                              hipStream_t stream) {
    const float* X    = (const float*)d_in[0];
    const float* W2_0 = (const float*)d_in[1];
    const float* W1_0 = (const float*)d_in[2];
    const float* W2_1 = (const float*)d_in[3];
    const float* W1_1 = (const float*)d_in[4];
    const float* W2_2 = (const float*)d_in[5];
    const float* W1_2 = (const float*)d_in[6];
    const float* Wf1  = (const float*)d_in[7];
    const float* Wf2  = (const float*)d_in[8];
    const int* src = (const int*)d_in[9];
    const int* dst = (const int*)d_in[10];
    float* out = (float*)d_out;

    const int n_edges = in_sizes[9];
    const int n_nodes = in_sizes[0] / FEAT;

    const int nbk  = (n_nodes + 63) >> 6;          // coarse buckets (<=2048 for scan_k)
    const int nblk = (n_edges + EPB - 1) / EPB;    // binning blocks (~1221)

    const size_t h_elems = (size_t)n_nodes * RS;
    // aux layout (4B elems): A | B | nbr | packed | blockhist | btot | bbase | bucket_start | start
    const size_t offA   = 0;
    const size_t offB   = offA + h_elems;
    const size_t offNbr = offB + h_elems;
    const size_t offPk  = offNbr + (size_t)n_edges;
    const size_t offBh  = offPk + (size_t)n_edges;
    const size_t offBt  = offBh + (size_t)nblk * nbk;
    const size_t offBb  = offBt + (size_t)nbk;
    const size_t offBs  = offBb + (size_t)nbk;
    const size_t offSt  = offBs + (size_t)nbk + 1;
    const size_t aux_elems = offSt + (size_t)n_nodes + 1;

    // H must survive until final_k (which writes d_out) -> always in ws.
    float* H = (float*)d_ws;
    char* aux;
    if (ws_size >= (h_elems + aux_elems) * 4) {
        aux = (char*)d_ws + h_elems * 4;
    } else {
        // all aux dead before final_k writes out; use out's tail.
        size_t tail = ((size_t)out_size - aux_elems) & ~(size_t)15;
        aux = (char*)((float*)d_out + tail);
    }
    float* A       = (float*)(aux + offA * 4);
    float* B       = (float*)(aux + offB * 4);
    int* nbr       = (int*)(aux + offNbr * 4);
    int* packed    = (int*)(aux + offPk * 4);
    int* blockhist = (int*)(aux + offBh * 4);
    int* btot      = (int*)(aux + offBt * 4);
    int* bbase     = (int*)(aux + offBb * 4);
    int* bstart    = (int*)(aux + offBs * 4);
    int* start     = (int*)(aux + offSt * 4);

    const int nb = (n_nodes + 255) / 256;
    const int gb = (n_nodes * 4 + 255) / 256;
    const int fb = (n_nodes + 63) / 64;
    const int cb = (nbk + 255) / 256;
    const size_t lds_bins = (size_t)nbk * 4;

    // ---- CSR build (two-level counting sort; LDS cursors only) ----
    bin_hist_k<<<nblk, 256, lds_bins, stream>>>(dst, blockhist, n_edges, nbk);
    col_sum_k<<<cb, 256, 0, stream>>>(blockhist, btot, nbk, nblk);
    scan_k<<<1, 256, 0, stream>>>(btot, bbase, bstart, start, nbk, n_nodes, n_edges);
    col_off_k<<<cb, 256, 0, stream>>>(blockhist, bbase, nbk, nblk);
    bin_scatter_k<<<nblk, 256, lds_bins, stream>>>(src, dst, blockhist, packed, n_edges, nbk);
    csr_k<<<nbk, 256, 0, stream>>>(packed, bstart, nbr, start, n_nodes);

    // ---- Layer 0 ----
    pre_l0<<<nb, 256, 0, stream>>>(X, W2_0, A, B, n_nodes);
    gather_k<<<gb, 256, 0, stream>>>(A, B, W1_0, start, nbr, H, n_nodes);

    // ---- Layer 1 ----
    pre_small<<<nb, 256, 0, stream>>>(H, W2_1, A, B, n_nodes);
    gather_k<<<gb, 256, 0, stream>>>(A, B, W1_1, start, nbr, H, n_nodes);

    // ---- Layer 2 ----
    pre_small<<<nb, 256, 0, stream>>>(H, W2_2, A, B, n_nodes);
    gather_k<<<gb, 256, 0, stream>>>(A, B, W1_2, start, nbr, H, n_nodes);

    // ---- Final node MLP ----
    final_k<<<fb, 256, 0, stream>>>(H, Wf1, Wf2, out, n_nodes);
}

// Round 7
// 283.419 us; speedup vs baseline: 2.4097x; 2.4097x over previous
//
#include <hip/hip_runtime.h>

#define FEAT 64
#define HID 10
#define RS 16    // padded row stride (floats) -> 64B rows, one cache line
#define EPB 1024 // edges per block in binning passes (256 thr x 4) -> ~1221 blocks
#define BSH 6    // bucket shift: 64 nodes per bucket
#define CHK 32   // block-rows per chunk in column-prefix passes

// ---------- Layer-0 precompute: A = X @ W2[0:64,:], B = X @ W2[64:128,:] ----------
__global__ __launch_bounds__(256) void pre_l0(
    const float* __restrict__ X,    // [NN,64]
    const float* __restrict__ W2,   // [128,10]
    float* __restrict__ A,          // [NN,RS]
    float* __restrict__ B,          // [NN,RS]
    int n_nodes)
{
    __shared__ float w2[128 * 10];
    for (int i = threadIdx.x; i < 1280; i += 256) w2[i] = W2[i];
    __syncthreads();

    int n = blockIdx.x * 256 + threadIdx.x;
    if (n >= n_nodes) return;

    const float4* xr = reinterpret_cast<const float4*>(X + (size_t)n * FEAT);
    float a[10], b[10];
#pragma unroll
    for (int h = 0; h < 10; h++) { a[h] = 0.f; b[h] = 0.f; }

#pragma unroll
    for (int blk = 0; blk < 16; blk++) {
        float4 u = xr[blk];
        float xv[4] = { u.x, u.y, u.z, u.w };
#pragma unroll
        for (int j = 0; j < 4; j++) {
            int k = blk * 4 + j;
#pragma unroll
            for (int h = 0; h < 10; h++) {
                a[h] = fmaf(xv[j], w2[k * 10 + h], a[h]);
                b[h] = fmaf(xv[j], w2[(64 + k) * 10 + h], b[h]);
            }
        }
    }

    float4* Ar = reinterpret_cast<float4*>(A + (size_t)n * RS);
    float4* Br = reinterpret_cast<float4*>(B + (size_t)n * RS);
    Ar[0] = make_float4(a[0], a[1], a[2], a[3]);
    Ar[1] = make_float4(a[4], a[5], a[6], a[7]);
    Ar[2] = make_float4(a[8], a[9], 0.f, 0.f);
    Br[0] = make_float4(b[0], b[1], b[2], b[3]);
    Br[1] = make_float4(b[4], b[5], b[6], b[7]);
    Br[2] = make_float4(b[8], b[9], 0.f, 0.f);
}

// ---------- Layers 1/2 precompute: A = H @ W2[0:10,:], B = H @ W2[10:20,:] ----------
__global__ __launch_bounds__(256) void pre_small(
    const float* __restrict__ H,    // [NN,RS]
    const float* __restrict__ W2,   // [20,10]
    float* __restrict__ A,          // [NN,RS]
    float* __restrict__ B,          // [NN,RS]
    int n_nodes)
{
    __shared__ float w2[200];
    for (int i = threadIdx.x; i < 200; i += 256) w2[i] = W2[i];
    __syncthreads();

    int n = blockIdx.x * 256 + threadIdx.x;
    if (n >= n_nodes) return;

    const float4* hr = reinterpret_cast<const float4*>(H + (size_t)n * RS);
    float4 h0 = hr[0], h1 = hr[1], h2 = hr[2];
    float hv[10] = { h0.x, h0.y, h0.z, h0.w, h1.x, h1.y, h1.z, h1.w, h2.x, h2.y };

    float a[10], b[10];
#pragma unroll
    for (int h = 0; h < 10; h++) { a[h] = 0.f; b[h] = 0.f; }
#pragma unroll
    for (int k = 0; k < 10; k++) {
#pragma unroll
        for (int h = 0; h < 10; h++) {
            a[h] = fmaf(hv[k], w2[k * 10 + h], a[h]);
            b[h] = fmaf(hv[k], w2[(10 + k) * 10 + h], b[h]);
        }
    }

    float4* Ar = reinterpret_cast<float4*>(A + (size_t)n * RS);
    float4* Br = reinterpret_cast<float4*>(B + (size_t)n * RS);
    Ar[0] = make_float4(a[0], a[1], a[2], a[3]);
    Ar[1] = make_float4(a[4], a[5], a[6], a[7]);
    Ar[2] = make_float4(a[8], a[9], 0.f, 0.f);
    Br[0] = make_float4(b[0], b[1], b[2], b[3]);
    Br[1] = make_float4(b[4], b[5], b[6], b[7]);
    Br[2] = make_float4(b[8], b[9], 0.f, 0.f);
}

// ================= CSR build: two-level counting sort, LDS cursors only =================

// Pass 1: per-block histogram over coarse buckets (dst >> BSH). No global atomics.
__global__ __launch_bounds__(256) void bin_hist_k(
    const int* __restrict__ dst, int* __restrict__ blockhist, int n_edges, int nbk)
{
    extern __shared__ int hist[];  // nbk ints
    for (int i = threadIdx.x; i < nbk; i += 256) hist[i] = 0;
    __syncthreads();
    int base = blockIdx.x * EPB;
    for (int i = threadIdx.x; i < EPB; i += 256) {
        int e = base + i;
        if (e < n_edges) atomicAdd(&hist[dst[e] >> BSH], 1);  // LDS atomic
    }
    __syncthreads();
    int* row = blockhist + (size_t)blockIdx.x * nbk;
    for (int i = threadIdx.x; i < nbk; i += 256) row[i] = hist[i];
}

// Pass 2a: per-chunk column sums. grid = (ceil(nbk/256), nchk).
// Wave reads are contiguous in b -> fully coalesced.
__global__ __launch_bounds__(256) void colchunk_sum_k(
    const int* __restrict__ blockhist, int* __restrict__ chunksum,
    int nbk, int nblk)
{
    int b = blockIdx.x * 256 + threadIdx.x;
    int c = blockIdx.y;
    if (b >= nbk) return;
    int k0 = c * CHK;
    int k1 = min(k0 + CHK, nblk);
    int s = 0;
    for (int k = k0; k < k1; k++) s += blockhist[(size_t)k * nbk + b];
    chunksum[(size_t)c * nbk + b] = s;
}

// Pass 2b: per-column exclusive scan over chunks (nchk small); also writes btot.
__global__ __launch_bounds__(256) void chunk_scan_k(
    int* __restrict__ chunksum, int* __restrict__ btot, int nbk, int nchk)
{
    int b = blockIdx.x * 256 + threadIdx.x;
    if (b >= nbk) return;
    int run = 0;
    for (int c = 0; c < nchk; c++) {
        size_t idx = (size_t)c * nbk + b;
        int v = chunksum[idx];
        chunksum[idx] = run;
        run += v;
    }
    btot[b] = run;
}

// Pass 2c: single-block exclusive scan of btot (nbk <= 2048).
__global__ __launch_bounds__(256) void scan_k(
    const int* __restrict__ btot, int* __restrict__ bbase,
    int* __restrict__ bucket_start, int* __restrict__ start,
    int nbk, int n_nodes, int n_edges)
{
    __shared__ int ts[256];
    int t = threadIdx.x;
    int v[8];
    int s = 0;
#pragma unroll
    for (int j = 0; j < 8; j++) {
        int idx = t * 8 + j;
        v[j] = (idx < nbk) ? btot[idx] : 0;
        s += v[j];
    }
    ts[t] = s;
    __syncthreads();
    for (int off = 1; off < 256; off <<= 1) {
        int x = (t >= off) ? ts[t - off] : 0;
        __syncthreads();
        ts[t] += x;
        __syncthreads();
    }
    int run = ts[t] - s;
#pragma unroll
    for (int j = 0; j < 8; j++) {
        int idx = t * 8 + j;
        if (idx < nbk) { bbase[idx] = run; bucket_start[idx] = run; }
        run += v[j];
    }
    if (t == 255) { bucket_start[nbk] = n_edges; start[n_nodes] = n_edges; }
}

// Pass 2d: per-(chunk,column) running offsets. grid = (ceil(nbk/256), nchk).
// Coalesced read+write; replaces the serial col_off_k.
__global__ __launch_bounds__(256) void col_off2_k(
    int* __restrict__ blockhist, const int* __restrict__ chunksum,
    const int* __restrict__ bbase, int nbk, int nblk)
{
    int b = blockIdx.x * 256 + threadIdx.x;
    int c = blockIdx.y;
    if (b >= nbk) return;
    int k0 = c * CHK;
    int k1 = min(k0 + CHK, nblk);
    int run = bbase[b] + chunksum[(size_t)c * nbk + b];
    for (int k = k0; k < k1; k++) {
        size_t idx = (size_t)k * nbk + b;
        int v = blockhist[idx];
        blockhist[idx] = run;
        run += v;
    }
}

// Pass 3: bucket-grouped scatter of packed (dloc<<17 | src); cursors in LDS.
__global__ __launch_bounds__(256) void bin_scatter_k(
    const int* __restrict__ src, const int* __restrict__ dst,
    const int* __restrict__ blockhist, int* __restrict__ packed,
    int n_edges, int nbk)
{
    extern __shared__ int cur[];  // nbk ints
    const int* row = blockhist + (size_t)blockIdx.x * nbk;
    for (int i = threadIdx.x; i < nbk; i += 256) cur[i] = row[i];
    __syncthreads();
    int base = blockIdx.x * EPB;
    for (int i = threadIdx.x; i < EPB; i += 256) {
        int e = base + i;
        if (e < n_edges) {
            int d = dst[e];
            int pos = atomicAdd(&cur[d >> BSH], 1);  // LDS atomic
            packed[pos] = ((d & 63) << 17) | src[e];
        }
    }
}

// Pass 4: one block per bucket -> exact CSR (start + nbr), all cursors in LDS.
__global__ __launch_bounds__(256) void csr_k(
    const int* __restrict__ packed, const int* __restrict__ bucket_start,
    int* __restrict__ nbr, int* __restrict__ start, int n_nodes)
{
    __shared__ int hist[64];
    __shared__ int excl[64];
    __shared__ int cur[64];
    int b = blockIdx.x;
    int base = bucket_start[b];
    int end  = bucket_start[b + 1];
    if (threadIdx.x < 64) hist[threadIdx.x] = 0;
    __syncthreads();
    for (int i = base + threadIdx.x; i < end; i += 256)
        atomicAdd(&hist[packed[i] >> 17], 1);  // LDS atomic
    __syncthreads();
    if (threadIdx.x == 0) {
        int r = 0;
        for (int k = 0; k < 64; k++) { excl[k] = r; r += hist[k]; }
    }
    __syncthreads();
    if (threadIdx.x < 64) {
        cur[threadIdx.x] = excl[threadIdx.x];
        int node = (b << 6) + threadIdx.x;
        if (node < n_nodes) start[node] = base + excl[threadIdx.x];
    }
    __syncthreads();
    for (int i = base + threadIdx.x; i < end; i += 256) {
        int p = packed[i];
        int pos = base + atomicAdd(&cur[p >> 17], 1);  // LDS atomic
        nbr[pos] = p & 0x1FFFF;
    }
}

// ---------- Gather-aggregate (quad-per-node): H[n] = 0.1 * sum relu(relu(A[n]+B[s])@W1) ----------
__global__ __launch_bounds__(256) void gather_k(
    const float* __restrict__ A,
    const float* __restrict__ B,
    const float* __restrict__ W1,   // [10,10]
    const int* __restrict__ start,  // [NN+1]
    const int* __restrict__ nbr,    // [NE] src ids grouped by dst
    float* __restrict__ H,          // [NN,RS]
    int n_nodes)
{
    __shared__ float w1[100];
    for (int i = threadIdx.x; i < 100; i += 256) w1[i] = W1[i];
    __syncthreads();

    int t = blockIdx.x * 256 + threadIdx.x;
    int n = t >> 2;
    int q = t & 3;
    if (n >= n_nodes) return;

    const float4* ar = reinterpret_cast<const float4*>(A + (size_t)n * RS);
    float4 a0 = ar[0], a1 = ar[1], a2 = ar[2];
    float av[10] = { a0.x, a0.y, a0.z, a0.w, a1.x, a1.y, a1.z, a1.w, a2.x, a2.y };

    float acc[10];
#pragma unroll
    for (int h = 0; h < 10; h++) acc[h] = 0.f;

    int beg = start[n];
    int end = start[n + 1];
    for (int i = beg + q; i < end; i += 4) {
        int s = nbr[i];
        const float4* br = reinterpret_cast<const float4*>(B + (size_t)s * RS);
        float4 b0 = br[0], b1 = br[1], b2 = br[2];
        float pre[10] = { av[0] + b0.x, av[1] + b0.y, av[2] + b0.z, av[3] + b0.w,
                          av[4] + b1.x, av[5] + b1.y, av[6] + b1.z, av[7] + b1.w,
                          av[8] + b2.x, av[9] + b2.y };
#pragma unroll
        for (int j = 0; j < 10; j++) pre[j] = fmaxf(pre[j], 0.f);
#pragma unroll
        for (int h = 0; h < 10; h++) {
            float z = 0.f;
#pragma unroll
            for (int j = 0; j < 10; j++) z = fmaf(pre[j], w1[j * 10 + h], z);
            acc[h] += fmaxf(z, 0.f);
        }
    }

#pragma unroll
    for (int h = 0; h < 10; h++) acc[h] += __shfl_xor(acc[h], 1);
#pragma unroll
    for (int h = 0; h < 10; h++) acc[h] += __shfl_xor(acc[h], 2);

    if (q == 0) {
        float4* Hr = reinterpret_cast<float4*>(H + (size_t)n * RS);
        Hr[0] = make_float4(acc[0] * 0.1f, acc[1] * 0.1f, acc[2] * 0.1f, acc[3] * 0.1f);
        Hr[1] = make_float4(acc[4] * 0.1f, acc[5] * 0.1f, acc[6] * 0.1f, acc[7] * 0.1f);
        Hr[2] = make_float4(acc[8] * 0.1f, acc[9] * 0.1f, 0.f, 0.f);
    }
}

// ---------- Final node MLP (tiled): out = relu(relu(H@Wf1)@Wf2) ----------
__global__ __launch_bounds__(256) void final_k(
    const float* __restrict__ H,    // [NN,RS]
    const float* __restrict__ Wf1,  // [10,64]
    const float* __restrict__ Wf2,  // [64,64]
    float* __restrict__ out,        // [NN,64]
    int n_nodes)
{
    __shared__ float wf1[640];
    __shared__ float wf2s[64 * 64];
    __shared__ float tT[64 * 64];

    for (int i = threadIdx.x; i < 640; i += 256) wf1[i] = Wf1[i];
    {
        const float4* w2v = reinterpret_cast<const float4*>(Wf2);
        float4* w2s = reinterpret_cast<float4*>(wf2s);
        for (int i = threadIdx.x; i < 1024; i += 256) w2s[i] = w2v[i];
    }

    int node0 = blockIdx.x * 64;

    {
        int r = threadIdx.x & 63;
        int g = threadIdx.x >> 6;
        int node = node0 + r;
        float hv[10];
        if (node < n_nodes) {
            const float4* hr = reinterpret_cast<const float4*>(H + (size_t)node * RS);
            float4 h0 = hr[0], h1 = hr[1], h2 = hr[2];
            hv[0]=h0.x; hv[1]=h0.y; hv[2]=h0.z; hv[3]=h0.w;
            hv[4]=h1.x; hv[5]=h1.y; hv[6]=h1.z; hv[7]=h1.w;
            hv[8]=h2.x; hv[9]=h2.y;
        } else {
#pragma unroll
            for (int k = 0; k < 10; k++) hv[k] = 0.f;
        }
        __syncthreads();
#pragma unroll
        for (int j = 0; j < 16; j++) {
            int c = g * 16 + j;
            float v = 0.f;
#pragma unroll
            for (int k = 0; k < 10; k++) v = fmaf(hv[k], wf1[k * 64 + c], v);
            tT[c * 64 + r] = fmaxf(v, 0.f);
        }
    }
    __syncthreads();

    int r0 = (threadIdx.x >> 4) * 4;
    int c0 = (threadIdx.x & 15) * 4;
    float acc[4][4];
#pragma unroll
    for (int i = 0; i < 4; i++)
#pragma unroll
        for (int j = 0; j < 4; j++) acc[i][j] = 0.f;

    for (int k = 0; k < 64; k++) {
        float4 a = *reinterpret_cast<const float4*>(&tT[k * 64 + r0]);
        float4 b = *reinterpret_cast<const float4*>(&wf2s[k * 64 + c0]);
        float av[4] = { a.x, a.y, a.z, a.w };
        float bv[4] = { b.x, b.y, b.z, b.w };
#pragma unroll
        for (int i = 0; i < 4; i++)
#pragma unroll
            for (int j = 0; j < 4; j++)
                acc[i][j] = fmaf(av[i], bv[j], acc[i][j]);
    }

#pragma unroll
    for (int i = 0; i < 4; i++) {
        int node = node0 + r0 + i;
        if (node < n_nodes) {
            float4 o = make_float4(fmaxf(acc[i][0], 0.f), fmaxf(acc[i][1], 0.f),
                                   fmaxf(acc[i][2], 0.f), fmaxf(acc[i][3], 0.f));
            *reinterpret_cast<float4*>(&out[(size_t)node * FEAT + c0]) = o;
        }
    }
}

extern "C" void kernel_launch(void* const* d_in, const int* in_sizes, int n_in,
                              void* d_out, int out_size, void* d_ws, size_t ws_size,
                              hipStream_t stream) {
    const float* X    = (const float*)d_in[0];
    const float* W2_0 = (const float*)d_in[1];
    const float* W1_0 = (const float*)d_in[2];
    const float* W2_1 = (const float*)d_in[3];
    const float* W1_1 = (const float*)d_in[4];
    const float* W2_2 = (const float*)d_in[5];
    const float* W1_2 = (const float*)d_in[6];
    const float* Wf1  = (const float*)d_in[7];
    const float* Wf2  = (const float*)d_in[8];
    const int* src = (const int*)d_in[9];
    const int* dst = (const int*)d_in[10];
    float* out = (float*)d_out;

    const int n_edges = in_sizes[9];
    const int n_nodes = in_sizes[0] / FEAT;

    const int nbk  = (n_nodes + 63) >> 6;          // coarse buckets (<=2048 for scan_k)
    const int nblk = (n_edges + EPB - 1) / EPB;    // binning blocks (~1221)
    const int nchk = (nblk + CHK - 1) / CHK;       // column-prefix chunks (~39)

    const size_t h_elems = (size_t)n_nodes * RS;
    // aux layout (4B elems): A | B | nbr | packed | blockhist | chunksum | btot | bbase | bucket_start | start
    const size_t offA   = 0;
    const size_t offB   = offA + h_elems;
    const size_t offNbr = offB + h_elems;
    const size_t offPk  = offNbr + (size_t)n_edges;
    const size_t offBh  = offPk + (size_t)n_edges;
    const size_t offCs  = offBh + (size_t)nblk * nbk;
    const size_t offBt  = offCs + (size_t)nchk * nbk;
    const size_t offBb  = offBt + (size_t)nbk;
    const size_t offBs  = offBb + (size_t)nbk;
    const size_t offSt  = offBs + (size_t)nbk + 1;
    const size_t aux_elems = offSt + (size_t)n_nodes + 1;

    // H must survive until final_k (which writes d_out) -> always in ws.
    float* H = (float*)d_ws;
    char* aux;
    if (ws_size >= (h_elems + aux_elems) * 4) {
        aux = (char*)d_ws + h_elems * 4;
    } else {
        // all aux dead before final_k writes out; use out's tail.
        size_t tail = ((size_t)out_size - aux_elems) & ~(size_t)15;
        aux = (char*)((float*)d_out + tail);
    }
    float* A        = (float*)(aux + offA * 4);
    float* B        = (float*)(aux + offB * 4);
    int* nbr        = (int*)(aux + offNbr * 4);
    int* packed     = (int*)(aux + offPk * 4);
    int* blockhist  = (int*)(aux + offBh * 4);
    int* chunksum   = (int*)(aux + offCs * 4);
    int* btot       = (int*)(aux + offBt * 4);
    int* bbase      = (int*)(aux + offBb * 4);
    int* bstart     = (int*)(aux + offBs * 4);
    int* start      = (int*)(aux + offSt * 4);

    const int nb = (n_nodes + 255) / 256;
    const int gb = (n_nodes * 4 + 255) / 256;
    const int fb = (n_nodes + 63) / 64;
    const int cb = (nbk + 255) / 256;
    const size_t lds_bins = (size_t)nbk * 4;

    // ---- CSR build (two-level counting sort; LDS cursors; parallel column prefix) ----
    bin_hist_k<<<nblk, 256, lds_bins, stream>>>(dst, blockhist, n_edges, nbk);
    colchunk_sum_k<<<dim3(cb, nchk), 256, 0, stream>>>(blockhist, chunksum, nbk, nblk);
    chunk_scan_k<<<cb, 256, 0, stream>>>(chunksum, btot, nbk, nchk);
    scan_k<<<1, 256, 0, stream>>>(btot, bbase, bstart, start, nbk, n_nodes, n_edges);
    col_off2_k<<<dim3(cb, nchk), 256, 0, stream>>>(blockhist, chunksum, bbase, nbk, nblk);
    bin_scatter_k<<<nblk, 256, lds_bins, stream>>>(src, dst, blockhist, packed, n_edges, nbk);
    csr_k<<<nbk, 256, 0, stream>>>(packed, bstart, nbr, start, n_nodes);

    // ---- Layer 0 ----
    pre_l0<<<nb, 256, 0, stream>>>(X, W2_0, A, B, n_nodes);
    gather_k<<<gb, 256, 0, stream>>>(A, B, W1_0, start, nbr, H, n_nodes);

    // ---- Layer 1 ----
    pre_small<<<nb, 256, 0, stream>>>(H, W2_1, A, B, n_nodes);
    gather_k<<<gb, 256, 0, stream>>>(A, B, W1_1, start, nbr, H, n_nodes);

    // ---- Layer 2 ----
    pre_small<<<nb, 256, 0, stream>>>(H, W2_2, A, B, n_nodes);
    gather_k<<<gb, 256, 0, stream>>>(A, B, W1_2, start, nbr, H, n_nodes);

    // ---- Final node MLP ----
    final_k<<<fb, 256, 0, stream>>>(H, Wf1, Wf2, out, n_nodes);
}